// Round 11
// baseline (1134.303 us; speedup 1.0000x reference)
//
#include <hip/hip_runtime.h>

#define NN 100000
#define NE 1600000
#define CH 4096                                  // edges per chunk (build)
#define NCHUNK ((NE + CH - 1) / CH)              // 391
#define NBUCK ((NN + 255) / 256)                 // 391 (256-node buckets)
#define SUB 4                                    // edge sub-blocks per bucket

__device__ __forceinline__ float wave_red(float v) {
#pragma unroll
    for (int off = 32; off > 0; off >>= 1) v += __shfl_down(v, off, 64);
    return v;
}

// ---------------- build phase: bucket sort, zero global atomics --------------
__global__ __launch_bounds__(256) void hist_kernel(
    const int* __restrict__ ei, int* __restrict__ hist)
{
    __shared__ int h[NBUCK];
    int t = threadIdx.x, c = blockIdx.x;
    for (int b = t; b < NBUCK; b += 256) h[b] = 0;
    __syncthreads();
    int base = c * CH;
    for (int i = t; i < CH; i += 256) {
        int e = base + i;
        if (e < NE) atomicAdd(&h[ei[e] >> 8], 1);
    }
    __syncthreads();
    for (int b = t; b < NBUCK; b += 256) hist[c * NBUCK + b] = h[b];
}

__global__ __launch_bounds__(512) void bscan_kernel(
    const int* __restrict__ hist, int* __restrict__ baseT, int* __restrict__ colTotal)
{
    __shared__ int buf[2][512];
    int b = blockIdx.x, t = threadIdx.x;
    int v = (t < NCHUNK) ? hist[t * NBUCK + b] : 0;
    buf[0][t] = v;
    __syncthreads();
    int src = 0;
    for (int d = 1; d < 512; d <<= 1) {
        int nv = buf[src][t] + ((t >= d) ? buf[src][t - d] : 0);
        buf[src ^ 1][t] = nv;
        src ^= 1;
        __syncthreads();
    }
    if (t < NCHUNK) baseT[b * NCHUNK + t] = buf[src][t] - v;   // exclusive over chunks
    if (t == NCHUNK - 1) colTotal[b] = buf[src][t];
}

__global__ __launch_bounds__(512) void boff_kernel(
    const int* __restrict__ colTotal, int* __restrict__ b_off)
{
    __shared__ int buf[2][512];
    int t = threadIdx.x;
    int v = (t < NBUCK) ? colTotal[t] : 0;
    buf[0][t] = v;
    __syncthreads();
    int src = 0;
    for (int d = 1; d < 512; d <<= 1) {
        int nv = buf[src][t] + ((t >= d) ? buf[src][t - d] : 0);
        buf[src ^ 1][t] = nv;
        src ^= 1;
        __syncthreads();
    }
    if (t < NBUCK) b_off[t] = buf[src][t] - v;
    if (t == NBUCK - 1) b_off[NBUCK] = buf[src][t];            // = NE
}

__global__ __launch_bounds__(256) void fillb_kernel(
    const int* __restrict__ ei, const float* __restrict__ eattr,
    const int* __restrict__ baseT, const int* __restrict__ b_off,
    float4* __restrict__ rec)
{
    __shared__ int sslot[NBUCK];
    int t = threadIdx.x, c = blockIdx.x;
    for (int b = t; b < NBUCK; b += 256)
        sslot[b] = b_off[b] + baseT[b * NCHUNK + c];
    __syncthreads();
    int base = c * CH;
    for (int i = t; i < CH; i += 256) {
        int e = base + i;
        if (e < NE) {
            int row = ei[e];
            int slot = atomicAdd(&sslot[row >> 8], 1);
            float2 ea = reinterpret_cast<const float2*>(eattr)[e];
            float4 v;
            v.x = __int_as_float(row);
            v.y = __int_as_float(ei[NE + e]);
            v.z = ea.x; v.w = ea.y;
            rec[slot] = v;
        }
    }
}

// ======== edge kernel: PINNED register weights + last-arriver node MLP =======
// r10's registerization was DEFEATED (VGPR=36: compiler re-sank the uniform
// weight loads as in-loop s_loads). ISA fact: SMEM and DS share lgkmcnt and
// SMEM returns OUT-OF-ORDER -> any loop mixing s_load weights with ds_read
// forces full lgkmcnt(0) drains every iteration (~10-20 cy/edge = the pinned
// invariant). Fix: asm volatile("" : "+v"(w)) pins each weight in a VGPR
// (post-asm value is opaque; cannot be rematerialized). gterm+bias folded
// into sPr staging. Inner loop now has ZERO scalar memory ops.
// Node MLP fused via last-arriver (pagg + threadfence + per-bucket counter).
template <bool WRITE_EMB, bool NEED_SUM>
__global__ __launch_bounds__(256, 1) void edge_kernel(
    float4* __restrict__ rec, const int* __restrict__ b_off,
    const float* __restrict__ gptr,
    const float* __restrict__ eW1, const float* __restrict__ eB1,
    const float* __restrict__ eW2, const float* __restrict__ eB2,
    const float* __restrict__ xin,
    const float* __restrict__ nW1, const float* __restrict__ nB1,
    const float* __restrict__ nW2, const float* __restrict__ nB2,
    float2* __restrict__ pagg, int* __restrict__ cnt,
    float* __restrict__ xout, float* __restrict__ sums)
{
    __shared__ float sPr[256][20];               // padded rows, b128-aligned
    __shared__ float sagg[256][2];
    __shared__ float redE[4][2];
    __shared__ float redN[4][8];
    __shared__ int   isLast;
    int tid = threadIdx.x;
    int b = blockIdx.x >> 2, s = blockIdx.x & 3;
    int n0 = b << 8;
    sagg[tid][0] = 0.f; sagg[tid][1] = 0.f;

    float gval = gptr[0];
    int nrow = n0 + tid;
    if (nrow < NN) {
        // row-projection + gterm + bias folded, staged once per block
        const float4* xi = reinterpret_cast<const float4*>(xin + (size_t)nrow * 8);
        float4 a0 = xi[0], a1 = xi[1];
        float xv[8] = {a0.x, a0.y, a0.z, a0.w, a1.x, a1.y, a1.z, a1.w};
        float pr[16];
#pragma unroll
        for (int q = 0; q < 16; q++) pr[q] = eB1[q] + gval * eW1[q];
#pragma unroll
        for (int k = 0; k < 8; k++) {
            float v = xv[k];
#pragma unroll
            for (int q = 0; q < 16; q++) pr[q] += v * eW1[(1 + k) * 16 + q];
        }
        float4* pw = reinterpret_cast<float4*>(&sPr[tid][0]);
#pragma unroll
        for (int t4 = 0; t4 < 4; t4++)
            pw[t4] = make_float4(pr[4*t4], pr[4*t4+1], pr[4*t4+2], pr[4*t4+3]);
    }
    __syncthreads();

    // ---- load + PIN edge-loop weights in VGPRs (192 regs, loaded once) ----
    float cw[128], aw[32], ow[32];
    {
        const float4* W4 = reinterpret_cast<const float4*>(eW1 + 9 * 16);
#pragma unroll
        for (int i = 0; i < 32; i++) {
            float4 w = W4[i];
            cw[4*i] = w.x; cw[4*i+1] = w.y; cw[4*i+2] = w.z; cw[4*i+3] = w.w;
        }
        const float4* A4 = reinterpret_cast<const float4*>(eW1 + 17 * 16);
#pragma unroll
        for (int i = 0; i < 8; i++) {
            float4 w = A4[i];
            aw[4*i] = w.x; aw[4*i+1] = w.y; aw[4*i+2] = w.z; aw[4*i+3] = w.w;
        }
        const float4* O4 = reinterpret_cast<const float4*>(eW2);
#pragma unroll
        for (int i = 0; i < 8; i++) {
            float4 w = O4[i];
            ow[4*i] = w.x; ow[4*i+1] = w.y; ow[4*i+2] = w.z; ow[4*i+3] = w.w;
        }
    }
#pragma unroll
    for (int i = 0; i < 128; i++) asm volatile("" : "+v"(cw[i]));
#pragma unroll
    for (int i = 0; i < 32; i++)  asm volatile("" : "+v"(aw[i]));
#pragma unroll
    for (int i = 0; i < 32; i++)  asm volatile("" : "+v"(ow[i]));
    float b20 = eB2[0], b21 = eB2[1];

    int e0b = b_off[b], e1b = b_off[b + 1];
    int qlen = (e1b - e0b + SUB - 1) / SUB;
    int es = e0b + s * qlen;
    int ee = min(e1b, es + qlen);

    float t0 = 0.f, t1 = 0.f;
    for (int e = es + tid; e < ee; e += 256) {
        float4 r = rec[e];
        int li  = __float_as_int(r.x) - n0;
        int col = __float_as_int(r.y);
        const float4* xc4 = reinterpret_cast<const float4*>(xin + (size_t)col * 8);
        float4 c0 = xc4[0], c1 = xc4[1];
        const float4* pr4 = reinterpret_cast<const float4*>(&sPr[li][0]);
        float4 p0 = pr4[0], p1 = pr4[1], p2 = pr4[2], p3 = pr4[3];
        float h[16];
        h[0]  = p0.x; h[1]  = p0.y; h[2]  = p0.z; h[3]  = p0.w;
        h[4]  = p1.x; h[5]  = p1.y; h[6]  = p1.z; h[7]  = p1.w;
        h[8]  = p2.x; h[9]  = p2.y; h[10] = p2.z; h[11] = p2.w;
        h[12] = p3.x; h[13] = p3.y; h[14] = p3.z; h[15] = p3.w;
        float xc[8] = {c0.x, c0.y, c0.z, c0.w, c1.x, c1.y, c1.z, c1.w};
#pragma unroll
        for (int k = 0; k < 8; k++) {
            float v = xc[k];
#pragma unroll
            for (int q = 0; q < 16; q++) h[q] += v * cw[k * 16 + q];
        }
#pragma unroll
        for (int q = 0; q < 16; q++) h[q] += r.z * aw[q] + r.w * aw[16 + q];
        float s0 = b20, s1 = b21;
#pragma unroll
        for (int q = 0; q < 16; q++) {
            float rr = fmaxf(h[q], 0.f);
            s0 += rr * ow[2 * q];
            s1 += rr * ow[2 * q + 1];
        }
        if (WRITE_EMB)
            reinterpret_cast<float2*>(rec)[2 * e + 1] = make_float2(s0, s1);
        atomicAdd(&sagg[li][0], s0);
        atomicAdd(&sagg[li][1], s1);
        t0 += s0; t1 += s1;
    }

    if (NEED_SUM) {
        float r0 = wave_red(t0), r1 = wave_red(t1);
        int wave = tid >> 6, lane = tid & 63;
        if (lane == 0) { redE[wave][0] = r0; redE[wave][1] = r1; }
    }
    __syncthreads();   // sagg complete (and redE visible)
    pagg[((size_t)s * NBUCK + b) * 256 + tid] =
        make_float2(sagg[tid][0], sagg[tid][1]);
    if (NEED_SUM && tid == 0) {
        atomicAdd(&sums[0], redE[0][0] + redE[1][0] + redE[2][0] + redE[3][0]);
        atomicAdd(&sums[1], redE[0][1] + redE[1][1] + redE[2][1] + redE[3][1]);
    }
    __threadfence();                             // release pagg writes
    if (tid == 0) isLast = (atomicAdd(&cnt[b], 1) == SUB - 1);
    __syncthreads();
    if (!isLast) return;

    // ------------- last-arriver: node MLP for this bucket --------------------
    __threadfence();                             // acquire all SUB pagg slabs
    float out[8];
#pragma unroll
    for (int m = 0; m < 8; m++) out[m] = 0.f;
    int n = n0 + tid;
    if (n < NN) {
        float ag0 = 0.f, ag1 = 0.f;
#pragma unroll
        for (int ss = 0; ss < SUB; ss++) {
            float2 p = pagg[((size_t)ss * NBUCK + b) * 256 + tid];
            ag0 += p.x; ag1 += p.y;
        }
        float in[11];
        in[0] = gval;
        const float4* xi = reinterpret_cast<const float4*>(xin + (size_t)n * 8);
        float4 a0 = xi[0], a1 = xi[1];
        in[1] = a0.x; in[2] = a0.y; in[3] = a0.z; in[4] = a0.w;
        in[5] = a1.x; in[6] = a1.y; in[7] = a1.z; in[8] = a1.w;
        in[9] = ag0; in[10] = ag1;

        float h[16];
#pragma unroll
        for (int q = 0; q < 16; q++) h[q] = nB1[q];
#pragma unroll
        for (int k = 0; k < 11; k++) {
            float v = in[k];
#pragma unroll
            for (int q = 0; q < 16; q++) h[q] += v * nW1[k * 16 + q];
        }
#pragma unroll
        for (int m = 0; m < 8; m++) out[m] = nB2[m];
#pragma unroll
        for (int q = 0; q < 16; q++) {
            float hq = fmaxf(h[q], 0.f);
#pragma unroll
            for (int m = 0; m < 8; m++) out[m] += hq * nW2[q * 8 + m];
        }
        float4* xo = reinterpret_cast<float4*>(xout + (size_t)n * 8);
        xo[0] = make_float4(out[0], out[1], out[2], out[3]);
        xo[1] = make_float4(out[4], out[5], out[6], out[7]);
    }
    if (NEED_SUM) {
        float r[8];
#pragma unroll
        for (int m = 0; m < 8; m++) r[m] = wave_red(out[m]);
        int wave = tid >> 6, lane = tid & 63;
        if (lane == 0) {
#pragma unroll
            for (int m = 0; m < 8; m++) redN[wave][m] = r[m];
        }
        __syncthreads();
        if (tid == 0) {
#pragma unroll
            for (int m = 0; m < 8; m++) {
                float sv = redN[0][m] + redN[1][m] + redN[2][m] + redN[3][m];
                atomicAdd(&sums[2 + m], sv);
            }
        }
    }
}

// ---------------- global block: MLP(11->16->1), single thread ----------------
__global__ void glob_kernel(const float* __restrict__ sums,
                            const float* __restrict__ gold,
                            const float* __restrict__ W1, const float* __restrict__ B1,
                            const float* __restrict__ W2, const float* __restrict__ B2,
                            float* __restrict__ gnew)
{
    if (threadIdx.x == 0 && blockIdx.x == 0) {
        float in[11];
#pragma unroll
        for (int j = 0; j < 8; j++) in[j] = sums[2 + j] * (1.0f / NN);
        in[8] = sums[0] * (1.0f / NE);
        in[9] = sums[1] * (1.0f / NE);
        in[10] = gold[0];
        float acc = B2[0];
#pragma unroll
        for (int j = 0; j < 16; j++) {
            float h = B1[j];
#pragma unroll
            for (int k = 0; k < 11; k++) h += in[k] * W1[k * 16 + j];
            acc += fmaxf(h, 0.f) * W2[j];
        }
        gnew[0] = acc;
    }
}

extern "C" void kernel_launch(void* const* d_in, const int* in_sizes, int n_in,
                              void* d_out, int out_size, void* d_ws, size_t ws_size,
                              hipStream_t stream) {
    const float* x     = (const float*)d_in[0];
    const int*   ei    = (const int*)d_in[1];
    const float* eattr = (const float*)d_in[2];
    const float* g     = (const float*)d_in[3];
    const float* eW1 = (const float*)d_in[4];
    const float* eB1 = (const float*)d_in[5];
    const float* eW2 = (const float*)d_in[6];
    const float* eB2 = (const float*)d_in[7];
    const float* nW1 = (const float*)d_in[8];
    const float* nB1 = (const float*)d_in[9];
    const float* nW2 = (const float*)d_in[10];
    const float* nB2 = (const float*)d_in[11];
    const float* gW1 = (const float*)d_in[12];
    const float* gB1 = (const float*)d_in[13];
    const float* gW2 = (const float*)d_in[14];
    const float* gB2 = (const float*)d_in[15];
    float* out = (float*)d_out;

    char* ws = (char*)d_ws;
    float*  xb0   = (float*)(ws);                  // 3,200,000
    float*  xb1   = (float*)(ws + 3200000);        // 3,200,000 -> 6,400,000
    int*    b_off = (int*)  (ws + 6400000);        // 392*4 -> pad 1,600
    float*  sums  = (float*)(ws + 6401600);        // 128 B
    int*    cnt   = (int*)  (ws + 6401728);        // 3*391*4 = 4,692 -> pad 4,800
    float*  g1    = (float*)(ws + 6406528);
    float*  g2    = g1 + 1;
    float4* rec   = (float4*)(ws + 6406592);       // 25,600,000 -> 32,006,592
    float2* pagg  = (float2*)(ws + 32006592);      // 4*391*256*8 = 3,203,072 -> 35,209,664
    // build-phase temporaries alias xb1 (dead until layer-1 node phase):
    int*    hist     = (int*)xb1;                          // 391*391*4 = 611,524
    int*    baseT    = (int*)((char*)xb1 + 611584);        // 611,524
    int*    colTotal = (int*)((char*)xb1 + 1223168);       // 1,564

    dim3 blk(256);
    dim3 cgrid(NCHUNK);                            // 391 chunks
    dim3 bgrid(NBUCK);                             // 391 buckets
    dim3 egrid(NBUCK * SUB);                       // 1564 edge sub-blocks

    // ---- bucket-sort build (no global atomics) ----
    hipMemsetAsync(sums, 0, 4928, stream);         // sums + cnt[3][NBUCK]
    hist_kernel<<<cgrid, blk, 0, stream>>>(ei, hist);
    bscan_kernel<<<bgrid, 512, 0, stream>>>(hist, baseT, colTotal);
    boff_kernel<<<1, 512, 0, stream>>>(colTotal, b_off);
    fillb_kernel<<<cgrid, blk, 0, stream>>>(ei, eattr, baseT, b_off, rec);

    // ---- layer 0: x(d_in) -> xb0; rec.zw: ea -> L0 edge emb ----
    edge_kernel<true, true><<<egrid, blk, 0, stream>>>(
        rec, b_off, g, eW1, eB1, eW2, eB2, x,
        nW1, nB1, nW2, nB2, pagg, cnt, xb0, sums);
    glob_kernel<<<1, 64, 0, stream>>>(sums, g, gW1, gB1, gW2, gB2, g1);

    // ---- layer 1: xb0 -> xb1; rec.zw: L0 -> L1 emb ----
    edge_kernel<true, true><<<egrid, blk, 0, stream>>>(
        rec, b_off, g1, eW1 + 304, eB1 + 16, eW2 + 32, eB2 + 2, xb0,
        nW1 + 176, nB1 + 16, nW2 + 128, nB2 + 8, pagg, cnt + NBUCK, xb1, sums + 16);
    glob_kernel<<<1, 64, 0, stream>>>(sums + 16, g1, gW1 + 176, gB1 + 16, gW2 + 16, gB2 + 1, g2);

    // ---- layer 2: xb1 -> d_out; no emb rewrite, no sums ----
    edge_kernel<false, false><<<egrid, blk, 0, stream>>>(
        rec, b_off, g2, eW1 + 608, eB1 + 32, eW2 + 64, eB2 + 4, xb1,
        nW1 + 352, nB1 + 32, nW2 + 256, nB2 + 16, pagg, cnt + 2 * NBUCK, out, sums);
}

// Round 12
// 997.543 us; speedup vs baseline: 1.1371x; 1.1371x over previous
//
#include <hip/hip_runtime.h>

#define NN 100000
#define NE 1600000
#define CH 4096                                  // edges per chunk (build)
#define NCHUNK ((NE + CH - 1) / CH)              // 391
#define NBUCK ((NN + 255) / 256)                 // 391 (256-node buckets)
#define SUB 4                                    // edge sub-blocks per bucket

__device__ __forceinline__ float wave_red(float v) {
#pragma unroll
    for (int off = 32; off > 0; off >>= 1) v += __shfl_down(v, off, 64);
    return v;
}

// ---------------- build phase: bucket sort, zero global atomics --------------
__global__ __launch_bounds__(256) void hist_kernel(
    const int* __restrict__ ei, int* __restrict__ hist)
{
    __shared__ int h[NBUCK];
    int t = threadIdx.x, c = blockIdx.x;
    for (int b = t; b < NBUCK; b += 256) h[b] = 0;
    __syncthreads();
    int base = c * CH;
    for (int i = t; i < CH; i += 256) {
        int e = base + i;
        if (e < NE) atomicAdd(&h[ei[e] >> 8], 1);
    }
    __syncthreads();
    for (int b = t; b < NBUCK; b += 256) hist[c * NBUCK + b] = h[b];
}

__global__ __launch_bounds__(512) void bscan_kernel(
    const int* __restrict__ hist, int* __restrict__ baseT, int* __restrict__ colTotal)
{
    __shared__ int buf[2][512];
    int b = blockIdx.x, t = threadIdx.x;
    int v = (t < NCHUNK) ? hist[t * NBUCK + b] : 0;
    buf[0][t] = v;
    __syncthreads();
    int src = 0;
    for (int d = 1; d < 512; d <<= 1) {
        int nv = buf[src][t] + ((t >= d) ? buf[src][t - d] : 0);
        buf[src ^ 1][t] = nv;
        src ^= 1;
        __syncthreads();
    }
    if (t < NCHUNK) baseT[b * NCHUNK + t] = buf[src][t] - v;   // exclusive over chunks
    if (t == NCHUNK - 1) colTotal[b] = buf[src][t];
}

__global__ __launch_bounds__(512) void boff_kernel(
    const int* __restrict__ colTotal, int* __restrict__ b_off)
{
    __shared__ int buf[2][512];
    int t = threadIdx.x;
    int v = (t < NBUCK) ? colTotal[t] : 0;
    buf[0][t] = v;
    __syncthreads();
    int src = 0;
    for (int d = 1; d < 512; d <<= 1) {
        int nv = buf[src][t] + ((t >= d) ? buf[src][t - d] : 0);
        buf[src ^ 1][t] = nv;
        src ^= 1;
        __syncthreads();
    }
    if (t < NBUCK) b_off[t] = buf[src][t] - v;
    if (t == NBUCK - 1) b_off[NBUCK] = buf[src][t];            // = NE
}

__global__ __launch_bounds__(256) void fillb_kernel(
    const int* __restrict__ ei, const float* __restrict__ eattr,
    const int* __restrict__ baseT, const int* __restrict__ b_off,
    float4* __restrict__ rec)
{
    __shared__ int sslot[NBUCK];
    int t = threadIdx.x, c = blockIdx.x;
    for (int b = t; b < NBUCK; b += 256)
        sslot[b] = b_off[b] + baseT[b * NCHUNK + c];
    __syncthreads();
    int base = c * CH;
    for (int i = t; i < CH; i += 256) {
        int e = base + i;
        if (e < NE) {
            int row = ei[e];
            int slot = atomicAdd(&sslot[row >> 8], 1);
            float2 ea = reinterpret_cast<const float2*>(eattr)[e];
            float4 v;
            v.x = __int_as_float(row);
            v.y = __int_as_float(ei[NE + e]);
            v.z = ea.x; v.w = ea.y;
            rec[slot] = v;
        }
    }
}

// ======== edge kernel: r10's proven 64us loop + last-arriver node MLP ========
// r10: SUB-split edge loop = 64us/dispatch (best measured), but separate node
// dispatches cost ~120us/launch total. r11 proved last-arriver is CORRECT on
// this HW but destroyed the loop with register pinning (VGPR=128 + scratch
// spill -> 380us; VALU 4%). This round: r10 loop body VERBATIM (compiler-
// managed weights, VGPR~36) + last-arriver node phase with the full release
// protocol (fence -> barrier -> flag; r11 lacked the barrier).
template <bool WRITE_EMB, bool NEED_SUM>
__global__ __launch_bounds__(256, 1) void edge_kernel(
    float4* __restrict__ rec, const int* __restrict__ b_off,
    const float* __restrict__ gptr,
    const float* __restrict__ eW1, const float* __restrict__ eB1,
    const float* __restrict__ eW2, const float* __restrict__ eB2,
    const float* __restrict__ xin,
    const float* __restrict__ nW1, const float* __restrict__ nB1,
    const float* __restrict__ nW2, const float* __restrict__ nB2,
    float2* __restrict__ pagg, int* __restrict__ cnt,
    float* __restrict__ xout, float* __restrict__ sums)
{
    __shared__ float sPr[256][20];               // padded rows, b128-aligned
    __shared__ float sagg[256][2];
    __shared__ float redE[4][2];
    __shared__ float redN[4][8];
    __shared__ int   isLast;
    int tid = threadIdx.x;
    int b = blockIdx.x >> 2, s = blockIdx.x & 3;
    int n0 = b << 8;
    sagg[tid][0] = 0.f; sagg[tid][1] = 0.f;

    float gval = gptr[0];
    int nrow = n0 + tid;
    if (nrow < NN) {
        // row-projection for own node (once per block)
        const float4* xi = reinterpret_cast<const float4*>(xin + (size_t)nrow * 8);
        float4 a0 = xi[0], a1 = xi[1];
        float xv[8] = {a0.x, a0.y, a0.z, a0.w, a1.x, a1.y, a1.z, a1.w};
        float pr[16];
#pragma unroll
        for (int q = 0; q < 16; q++) pr[q] = 0.f;
#pragma unroll
        for (int k = 0; k < 8; k++) {
            float v = xv[k];
#pragma unroll
            for (int q = 0; q < 16; q++) pr[q] += v * eW1[(1 + k) * 16 + q];
        }
        float4* pw = reinterpret_cast<float4*>(&sPr[tid][0]);
#pragma unroll
        for (int t4 = 0; t4 < 4; t4++)
            pw[t4] = make_float4(pr[4*t4], pr[4*t4+1], pr[4*t4+2], pr[4*t4+3]);
    }
    __syncthreads();

    float gterm[16];
#pragma unroll
    for (int q = 0; q < 16; q++) gterm[q] = eB1[q] + gval * eW1[q];
    float b20 = eB2[0], b21 = eB2[1];

    int e0b = b_off[b], e1b = b_off[b + 1];
    int qlen = (e1b - e0b + SUB - 1) / SUB;
    int es = e0b + s * qlen;
    int ee = min(e1b, es + qlen);

    float t0 = 0.f, t1 = 0.f;
    for (int e = es + tid; e < ee; e += 256) {
        float4 r = rec[e];
        int li  = __float_as_int(r.x) - n0;
        int col = __float_as_int(r.y);
        const float4* xc4 = reinterpret_cast<const float4*>(xin + (size_t)col * 8);
        float4 c0 = xc4[0], c1 = xc4[1];
        const float4* pr4 = reinterpret_cast<const float4*>(&sPr[li][0]);
        float4 p0 = pr4[0], p1 = pr4[1], p2 = pr4[2], p3 = pr4[3];
        float h[16];
        h[0]  = gterm[0]  + p0.x; h[1]  = gterm[1]  + p0.y;
        h[2]  = gterm[2]  + p0.z; h[3]  = gterm[3]  + p0.w;
        h[4]  = gterm[4]  + p1.x; h[5]  = gterm[5]  + p1.y;
        h[6]  = gterm[6]  + p1.z; h[7]  = gterm[7]  + p1.w;
        h[8]  = gterm[8]  + p2.x; h[9]  = gterm[9]  + p2.y;
        h[10] = gterm[10] + p2.z; h[11] = gterm[11] + p2.w;
        h[12] = gterm[12] + p3.x; h[13] = gterm[13] + p3.y;
        h[14] = gterm[14] + p3.z; h[15] = gterm[15] + p3.w;
        float xc[8] = {c0.x, c0.y, c0.z, c0.w, c1.x, c1.y, c1.z, c1.w};
#pragma unroll
        for (int k = 0; k < 8; k++) {
            float v = xc[k];
#pragma unroll
            for (int q = 0; q < 16; q++) h[q] += v * eW1[(9 + k) * 16 + q];
        }
#pragma unroll
        for (int q = 0; q < 16; q++)
            h[q] += r.z * eW1[17 * 16 + q] + r.w * eW1[18 * 16 + q];
        float s0 = b20, s1 = b21;
#pragma unroll
        for (int q = 0; q < 16; q++) {
            float rr = fmaxf(h[q], 0.f);
            s0 += rr * eW2[2 * q];
            s1 += rr * eW2[2 * q + 1];
        }
        if (WRITE_EMB) rec[e] = make_float4(r.x, r.y, s0, s1);
        atomicAdd(&sagg[li][0], s0);
        atomicAdd(&sagg[li][1], s1);
        t0 += s0; t1 += s1;
    }

    if (NEED_SUM) {
        float r0 = wave_red(t0), r1 = wave_red(t1);
        int wave = tid >> 6, lane = tid & 63;
        if (lane == 0) { redE[wave][0] = r0; redE[wave][1] = r1; }
    }
    __syncthreads();   // sagg complete (and redE visible)
    pagg[((size_t)s * NBUCK + b) * 256 + tid] =
        make_float2(sagg[tid][0], sagg[tid][1]);
    if (NEED_SUM && tid == 0) {
        atomicAdd(&sums[0], redE[0][0] + redE[1][0] + redE[2][0] + redE[3][0]);
        atomicAdd(&sums[1], redE[0][1] + redE[1][1] + redE[2][1] + redE[3][1]);
    }
    __threadfence();   // each thread drains ITS pagg write (device scope)
    __syncthreads();   // ALL drains complete before the flag is raised
    if (tid == 0) isLast = (atomicAdd(&cnt[b], 1) == SUB - 1);
    __syncthreads();
    if (!isLast) return;

    // ------------- last-arriver: node MLP for this bucket --------------------
    __threadfence();   // acquire: invalidate before reading other subs' pagg
    float out[8];
#pragma unroll
    for (int m = 0; m < 8; m++) out[m] = 0.f;
    int n = n0 + tid;
    if (n < NN) {
        float ag0 = 0.f, ag1 = 0.f;
#pragma unroll
        for (int ss = 0; ss < SUB; ss++) {
            float2 p = pagg[((size_t)ss * NBUCK + b) * 256 + tid];
            ag0 += p.x; ag1 += p.y;
        }
        float in[11];
        in[0] = gval;
        const float4* xi = reinterpret_cast<const float4*>(xin + (size_t)n * 8);
        float4 a0 = xi[0], a1 = xi[1];
        in[1] = a0.x; in[2] = a0.y; in[3] = a0.z; in[4] = a0.w;
        in[5] = a1.x; in[6] = a1.y; in[7] = a1.z; in[8] = a1.w;
        in[9] = ag0; in[10] = ag1;

        float h[16];
#pragma unroll
        for (int q = 0; q < 16; q++) h[q] = nB1[q];
#pragma unroll
        for (int k = 0; k < 11; k++) {
            float v = in[k];
#pragma unroll
            for (int q = 0; q < 16; q++) h[q] += v * nW1[k * 16 + q];
        }
#pragma unroll
        for (int m = 0; m < 8; m++) out[m] = nB2[m];
#pragma unroll
        for (int q = 0; q < 16; q++) {
            float hq = fmaxf(h[q], 0.f);
#pragma unroll
            for (int m = 0; m < 8; m++) out[m] += hq * nW2[q * 8 + m];
        }
        float4* xo = reinterpret_cast<float4*>(xout + (size_t)n * 8);
        xo[0] = make_float4(out[0], out[1], out[2], out[3]);
        xo[1] = make_float4(out[4], out[5], out[6], out[7]);
    }
    if (NEED_SUM) {
        float r[8];
#pragma unroll
        for (int m = 0; m < 8; m++) r[m] = wave_red(out[m]);
        int wave = tid >> 6, lane = tid & 63;
        if (lane == 0) {
#pragma unroll
            for (int m = 0; m < 8; m++) redN[wave][m] = r[m];
        }
        __syncthreads();
        if (tid == 0) {
#pragma unroll
            for (int m = 0; m < 8; m++) {
                float sv = redN[0][m] + redN[1][m] + redN[2][m] + redN[3][m];
                atomicAdd(&sums[2 + m], sv);
            }
        }
    }
}

// ---------------- global block: MLP(11->16->1), single thread ----------------
__global__ void glob_kernel(const float* __restrict__ sums,
                            const float* __restrict__ gold,
                            const float* __restrict__ W1, const float* __restrict__ B1,
                            const float* __restrict__ W2, const float* __restrict__ B2,
                            float* __restrict__ gnew)
{
    if (threadIdx.x == 0 && blockIdx.x == 0) {
        float in[11];
#pragma unroll
        for (int j = 0; j < 8; j++) in[j] = sums[2 + j] * (1.0f / NN);
        in[8] = sums[0] * (1.0f / NE);
        in[9] = sums[1] * (1.0f / NE);
        in[10] = gold[0];
        float acc = B2[0];
#pragma unroll
        for (int j = 0; j < 16; j++) {
            float h = B1[j];
#pragma unroll
            for (int k = 0; k < 11; k++) h += in[k] * W1[k * 16 + j];
            acc += fmaxf(h, 0.f) * W2[j];
        }
        gnew[0] = acc;
    }
}

extern "C" void kernel_launch(void* const* d_in, const int* in_sizes, int n_in,
                              void* d_out, int out_size, void* d_ws, size_t ws_size,
                              hipStream_t stream) {
    const float* x     = (const float*)d_in[0];
    const int*   ei    = (const int*)d_in[1];
    const float* eattr = (const float*)d_in[2];
    const float* g     = (const float*)d_in[3];
    const float* eW1 = (const float*)d_in[4];
    const float* eB1 = (const float*)d_in[5];
    const float* eW2 = (const float*)d_in[6];
    const float* eB2 = (const float*)d_in[7];
    const float* nW1 = (const float*)d_in[8];
    const float* nB1 = (const float*)d_in[9];
    const float* nW2 = (const float*)d_in[10];
    const float* nB2 = (const float*)d_in[11];
    const float* gW1 = (const float*)d_in[12];
    const float* gB1 = (const float*)d_in[13];
    const float* gW2 = (const float*)d_in[14];
    const float* gB2 = (const float*)d_in[15];
    float* out = (float*)d_out;

    char* ws = (char*)d_ws;
    float*  xb0   = (float*)(ws);                  // 3,200,000
    float*  xb1   = (float*)(ws + 3200000);        // 3,200,000 -> 6,400,000
    int*    b_off = (int*)  (ws + 6400000);        // 392*4 -> pad 1,600
    float*  sums  = (float*)(ws + 6401600);        // 128 B
    int*    cnt   = (int*)  (ws + 6401728);        // 3*391*4 = 4,692 -> pad 4,800
    float*  g1    = (float*)(ws + 6406528);
    float*  g2    = g1 + 1;
    float4* rec   = (float4*)(ws + 6406592);       // 25,600,000 -> 32,006,592
    float2* pagg  = (float2*)(ws + 32006592);      // 4*391*256*8 = 3,203,072 -> 35,209,664
    // build-phase temporaries alias xb1 (dead until layer-1 node phase):
    int*    hist     = (int*)xb1;                          // 391*391*4 = 611,524
    int*    baseT    = (int*)((char*)xb1 + 611584);        // 611,524
    int*    colTotal = (int*)((char*)xb1 + 1223168);       // 1,564

    dim3 blk(256);
    dim3 cgrid(NCHUNK);                            // 391 chunks
    dim3 bgrid(NBUCK);                             // 391 buckets
    dim3 egrid(NBUCK * SUB);                       // 1564 edge sub-blocks

    // ---- bucket-sort build (no global atomics) ----
    hipMemsetAsync(sums, 0, 4928, stream);         // sums + cnt[3][NBUCK]
    hist_kernel<<<cgrid, blk, 0, stream>>>(ei, hist);
    bscan_kernel<<<bgrid, 512, 0, stream>>>(hist, baseT, colTotal);
    boff_kernel<<<1, 512, 0, stream>>>(colTotal, b_off);
    fillb_kernel<<<cgrid, blk, 0, stream>>>(ei, eattr, baseT, b_off, rec);

    // ---- layer 0: x(d_in) -> xb0; rec.zw: ea -> L0 edge emb ----
    edge_kernel<true, true><<<egrid, blk, 0, stream>>>(
        rec, b_off, g, eW1, eB1, eW2, eB2, x,
        nW1, nB1, nW2, nB2, pagg, cnt, xb0, sums);
    glob_kernel<<<1, 64, 0, stream>>>(sums, g, gW1, gB1, gW2, gB2, g1);

    // ---- layer 1: xb0 -> xb1; rec.zw: L0 -> L1 emb ----
    edge_kernel<true, true><<<egrid, blk, 0, stream>>>(
        rec, b_off, g1, eW1 + 304, eB1 + 16, eW2 + 32, eB2 + 2, xb0,
        nW1 + 176, nB1 + 16, nW2 + 128, nB2 + 8, pagg, cnt + NBUCK, xb1, sums + 16);
    glob_kernel<<<1, 64, 0, stream>>>(sums + 16, g1, gW1 + 176, gB1 + 16, gW2 + 16, gB2 + 1, g2);

    // ---- layer 2: xb1 -> d_out; no emb rewrite, no sums ----
    edge_kernel<false, false><<<egrid, blk, 0, stream>>>(
        rec, b_off, g2, eW1 + 608, eB1 + 32, eW2 + 64, eB2 + 4, xb1,
        nW1 + 352, nB1 + 32, nW2 + 256, nB2 + 16, pagg, cnt + 2 * NBUCK, out, sums);
}

// Round 13
// 352.781 us; speedup vs baseline: 3.2153x; 2.8277x over previous
//
#include <hip/hip_runtime.h>

#define NN 100000
#define NE 1600000
#define CH 4096                                  // edges per chunk (build)
#define NCHUNK ((NE + CH - 1) / CH)              // 391
#define NBUCK ((NN + 255) / 256)                 // 391 (256-node buckets = fused blocks)

__device__ __forceinline__ float wave_red(float v) {
#pragma unroll
    for (int off = 32; off > 0; off >>= 1) v += __shfl_down(v, off, 64);
    return v;
}

// ---------------- build phase: bucket sort, zero global atomics --------------
__global__ __launch_bounds__(256) void hist_kernel(
    const int* __restrict__ ei, int* __restrict__ hist)
{
    __shared__ int h[NBUCK];
    int t = threadIdx.x, c = blockIdx.x;
    for (int b = t; b < NBUCK; b += 256) h[b] = 0;
    __syncthreads();
    int base = c * CH;
    for (int i = t; i < CH; i += 256) {
        int e = base + i;
        if (e < NE) atomicAdd(&h[ei[e] >> 8], 1);
    }
    __syncthreads();
    for (int b = t; b < NBUCK; b += 256) hist[c * NBUCK + b] = h[b];
}

__global__ __launch_bounds__(512) void bscan_kernel(
    const int* __restrict__ hist, int* __restrict__ baseT, int* __restrict__ colTotal)
{
    __shared__ int buf[2][512];
    int b = blockIdx.x, t = threadIdx.x;
    int v = (t < NCHUNK) ? hist[t * NBUCK + b] : 0;
    buf[0][t] = v;
    __syncthreads();
    int src = 0;
    for (int d = 1; d < 512; d <<= 1) {
        int nv = buf[src][t] + ((t >= d) ? buf[src][t - d] : 0);
        buf[src ^ 1][t] = nv;
        src ^= 1;
        __syncthreads();
    }
    if (t < NCHUNK) baseT[b * NCHUNK + t] = buf[src][t] - v;   // exclusive over chunks
    if (t == NCHUNK - 1) colTotal[b] = buf[src][t];
}

// also zeroes the 32-float sums area (replaces the memset dispatch)
__global__ __launch_bounds__(512) void boff_kernel(
    const int* __restrict__ colTotal, int* __restrict__ b_off, float* __restrict__ sums)
{
    __shared__ int buf[2][512];
    int t = threadIdx.x;
    if (t < 32) sums[t] = 0.f;
    int v = (t < NBUCK) ? colTotal[t] : 0;
    buf[0][t] = v;
    __syncthreads();
    int src = 0;
    for (int d = 1; d < 512; d <<= 1) {
        int nv = buf[src][t] + ((t >= d) ? buf[src][t - d] : 0);
        buf[src ^ 1][t] = nv;
        src ^= 1;
        __syncthreads();
    }
    if (t < NBUCK) b_off[t] = buf[src][t] - v;
    if (t == NBUCK - 1) b_off[NBUCK] = buf[src][t];            // = NE
}

__global__ __launch_bounds__(256) void fillb_kernel(
    const int* __restrict__ ei, const float* __restrict__ eattr,
    const int* __restrict__ baseT, const int* __restrict__ b_off,
    float4* __restrict__ rec)
{
    __shared__ int sslot[NBUCK];
    int t = threadIdx.x, c = blockIdx.x;
    for (int b = t; b < NBUCK; b += 256)
        sslot[b] = b_off[b] + baseT[b * NCHUNK + c];
    __syncthreads();
    int base = c * CH;
    for (int i = t; i < CH; i += 256) {
        int e = base + i;
        if (e < NE) {
            int row = ei[e];
            int slot = atomicAdd(&sslot[row >> 8], 1);
            float2 ea = reinterpret_cast<const float2*>(eattr)[e];
            float4 v;
            v.x = __int_as_float(row);
            v.y = __int_as_float(ei[NE + e]);
            v.z = ea.x; v.w = ea.y;
            rec[slot] = v;
        }
    }
}

// uniform glob MLP(11->16->1): ~200 flops on 10 sums + g. Computed redundantly
// per block (prologue) instead of as its own dispatch.
__device__ __forceinline__ float glob_eval(
    const float* __restrict__ sm, float gg,
    const float* __restrict__ W1, const float* __restrict__ B1,
    const float* __restrict__ W2, const float* __restrict__ B2)
{
    float in[11];
#pragma unroll
    for (int j = 0; j < 8; j++) in[j] = sm[2 + j] * (1.0f / NN);
    in[8] = sm[0] * (1.0f / NE);
    in[9] = sm[1] * (1.0f / NE);
    in[10] = gg;
    float acc = B2[0];
#pragma unroll
    for (int j = 0; j < 16; j++) {
        float h = B1[j];
#pragma unroll
        for (int k = 0; k < 11; k++) h += in[k] * W1[k * 16 + j];
        acc += fmaxf(h, 0.f) * W2[j];
    }
    return acc;
}

// ============ FUSED layer kernel: r5 structure verbatim + inline glob ========
// r5 (391 blocks x 1024 thr, in-loop gather, LDS agg) = best measured total
// (331.7us; fused 84us). r12 proved last-arriver/threadfence is poison on
// CDNA4 (per-block device fence x1564 -> 375us). This round changes ONLY
// overhead: glob chain inlined per-block (sums visible via stream ordering),
// memset folded into boff -> 12 dispatches down to 7. Hot loops untouched.
template <int LAYER, bool WRITE_REC, bool NEED_SUM>
__global__ __launch_bounds__(1024, 4) void fused_kernel(
    float4* __restrict__ rec, const int* __restrict__ b_off,
    const float* __restrict__ gold,
    const float* __restrict__ gW1, const float* __restrict__ gB1,
    const float* __restrict__ gW2, const float* __restrict__ gB2,
    const float* __restrict__ eW1, const float* __restrict__ eB1,
    const float* __restrict__ eW2, const float* __restrict__ eB2,
    const float* __restrict__ xin,
    const float* __restrict__ nW1, const float* __restrict__ nB1,
    const float* __restrict__ nW2, const float* __restrict__ nB2,
    float* __restrict__ xout, float* __restrict__ sumsBase)
{
    __shared__ float sPrT[16 * 256];             // 16 KB, transposed: [q*256+li]
    __shared__ float sagg[256][2];               // 2 KB
    __shared__ float redE[16][2];
    __shared__ float redN[4][8];
    int tid = threadIdx.x;
    if (tid < 512) ((float*)sagg)[tid] = 0.f;

    // ---- inline glob chain: g_{LAYER} from sums slabs (uniform, ~400 flops) --
    float gval = gold[0];
#pragma unroll
    for (int l = 0; l < LAYER; l++)
        gval = glob_eval(sumsBase + 16 * l, gval,
                         gW1 + 176 * l, gB1 + 16 * l, gW2 + 16 * l, gB2 + l);
    float* sums = sumsBase + 16 * LAYER;         // this layer's accumulation slab

    int n0 = blockIdx.x * 256;
    bool own = (tid < 256) && (n0 + tid < NN);
    if (own) {
        // row-projection for own node, computed in-block (128 FMAs, once)
        const float4* xi = reinterpret_cast<const float4*>(xin + (size_t)(n0 + tid) * 8);
        float4 a0 = xi[0], a1 = xi[1];
        float xv[8] = {a0.x, a0.y, a0.z, a0.w, a1.x, a1.y, a1.z, a1.w};
        float pr[16];
#pragma unroll
        for (int q = 0; q < 16; q++) pr[q] = 0.f;
#pragma unroll
        for (int k = 0; k < 8; k++) {
            float v = xv[k];
#pragma unroll
            for (int q = 0; q < 16; q++) pr[q] += v * eW1[(1 + k) * 16 + q];
        }
#pragma unroll
        for (int q = 0; q < 16; q++) sPrT[q * 256 + tid] = pr[q];
    }
    __syncthreads();

    int e0 = b_off[blockIdx.x], e1 = b_off[blockIdx.x + 1];

    float gterm[16];
#pragma unroll
    for (int q = 0; q < 16; q++) gterm[q] = eB1[q] + gval * eW1[q];

    float t0 = 0.f, t1 = 0.f;
    for (int e = e0 + tid; e < e1; e += 1024) {
        float4 r = rec[e];
        int row = __float_as_int(r.x);
        int col = __float_as_int(r.y);
        float ea0 = r.z, ea1 = r.w;
        int li = row - n0;
        const float4* xc4 = reinterpret_cast<const float4*>(xin + (size_t)col * 8);
        float4 c0 = xc4[0], c1 = xc4[1];
        float xc[8] = {c0.x, c0.y, c0.z, c0.w, c1.x, c1.y, c1.z, c1.w};
        float h[16];
#pragma unroll
        for (int q = 0; q < 16; q++) h[q] = gterm[q] + sPrT[q * 256 + li];
#pragma unroll
        for (int k = 0; k < 8; k++) {
            float v = xc[k];
#pragma unroll
            for (int q = 0; q < 16; q++) h[q] += v * eW1[(9 + k) * 16 + q];
        }
#pragma unroll
        for (int q = 0; q < 16; q++) {
            h[q] += ea0 * eW1[17 * 16 + q];
            h[q] += ea1 * eW1[18 * 16 + q];
        }
        float s0 = eB2[0], s1 = eB2[1];
#pragma unroll
        for (int q = 0; q < 16; q++) {
            float rr = fmaxf(h[q], 0.f);
            s0 += rr * eW2[2 * q];
            s1 += rr * eW2[2 * q + 1];
        }
        if (WRITE_REC) {
            float4 w;
            w.x = r.x; w.y = r.y; w.z = s0; w.w = s1;
            rec[e] = w;
        }
        atomicAdd(&sagg[li][0], s0);
        atomicAdd(&sagg[li][1], s1);
        t0 += s0; t1 += s1;
    }

    if (NEED_SUM) {
        float r0 = wave_red(t0);
        float r1 = wave_red(t1);
        int wave = tid >> 6, lane = tid & 63;
        if (lane == 0) { redE[wave][0] = r0; redE[wave][1] = r1; }
    }
    __syncthreads();   // sagg complete (and redE visible)
    if (NEED_SUM && tid == 0) {
        float s0 = 0.f, s1 = 0.f;
#pragma unroll
        for (int w = 0; w < 16; w++) { s0 += redE[w][0]; s1 += redE[w][1]; }
        atomicAdd(&sums[0], s0);
        atomicAdd(&sums[1], s1);
    }

    // ---------------- phase 2: node MLP (threads 0..255) ----------------
    float out[8];
#pragma unroll
    for (int m = 0; m < 8; m++) out[m] = 0.f;

    if (own) {
        int n = n0 + tid;
        float in[11];
        in[0] = gval;
        const float4* xi = reinterpret_cast<const float4*>(xin + (size_t)n * 8);
        float4 a0 = xi[0], a1 = xi[1];
        in[1] = a0.x; in[2] = a0.y; in[3] = a0.z; in[4] = a0.w;
        in[5] = a1.x; in[6] = a1.y; in[7] = a1.z; in[8] = a1.w;
        in[9] = sagg[tid][0]; in[10] = sagg[tid][1];

        float h[16];
#pragma unroll
        for (int q = 0; q < 16; q++) h[q] = nB1[q];
#pragma unroll
        for (int k = 0; k < 11; k++) {
            float v = in[k];
#pragma unroll
            for (int q = 0; q < 16; q++) h[q] += v * nW1[k * 16 + q];
        }
#pragma unroll
        for (int m = 0; m < 8; m++) out[m] = nB2[m];
#pragma unroll
        for (int q = 0; q < 16; q++) {
            float hq = fmaxf(h[q], 0.f);
#pragma unroll
            for (int m = 0; m < 8; m++) out[m] += hq * nW2[q * 8 + m];
        }
        float4* xo = reinterpret_cast<float4*>(xout + (size_t)n * 8);
        xo[0] = make_float4(out[0], out[1], out[2], out[3]);
        xo[1] = make_float4(out[4], out[5], out[6], out[7]);
    }
    if (NEED_SUM) {
        // owners are waves 0..3 only; reduce within those waves
        float r[8];
#pragma unroll
        for (int m = 0; m < 8; m++) r[m] = wave_red(out[m]);
        int wave = tid >> 6, lane = tid & 63;
        if (wave < 4 && lane == 0) {
#pragma unroll
            for (int m = 0; m < 8; m++) redN[wave][m] = r[m];
        }
        __syncthreads();
        if (tid == 0) {
#pragma unroll
            for (int m = 0; m < 8; m++) {
                float s = redN[0][m] + redN[1][m] + redN[2][m] + redN[3][m];
                atomicAdd(&sums[2 + m], s);
            }
        }
    }
}

extern "C" void kernel_launch(void* const* d_in, const int* in_sizes, int n_in,
                              void* d_out, int out_size, void* d_ws, size_t ws_size,
                              hipStream_t stream) {
    const float* x     = (const float*)d_in[0];
    const int*   ei    = (const int*)d_in[1];
    const float* eattr = (const float*)d_in[2];
    const float* g     = (const float*)d_in[3];
    const float* eW1 = (const float*)d_in[4];
    const float* eB1 = (const float*)d_in[5];
    const float* eW2 = (const float*)d_in[6];
    const float* eB2 = (const float*)d_in[7];
    const float* nW1 = (const float*)d_in[8];
    const float* nB1 = (const float*)d_in[9];
    const float* nW2 = (const float*)d_in[10];
    const float* nB2 = (const float*)d_in[11];
    const float* gW1 = (const float*)d_in[12];
    const float* gB1 = (const float*)d_in[13];
    const float* gW2 = (const float*)d_in[14];
    const float* gB2 = (const float*)d_in[15];
    float* out = (float*)d_out;

    char* ws = (char*)d_ws;
    float*  xb0   = (float*)(ws);                  // 3,200,000
    float*  xb1   = (float*)(ws + 3200000);        // 3,200,000 -> 6,400,000
    int*    b_off = (int*)  (ws + 6400000);        // 392*4 = 1,568 -> pad 1,600
    float*  sums  = (float*)(ws + 6401600);        // 2 slabs x 16 floats = 128 B
    float4* rec   = (float4*)(ws + 6401792);       // 25,600,000 -> 32,001,792 total
    // build-phase temporaries alias xb1 (dead until layer-1 phase 2):
    int*    hist     = (int*)xb1;                          // 391*391*4 = 611,524
    int*    baseT    = (int*)((char*)xb1 + 611584);        // 611,524
    int*    colTotal = (int*)((char*)xb1 + 1223168);       // 1,564

    dim3 blk(256);
    dim3 fblk(1024);
    dim3 cgrid(NCHUNK);                            // 391 chunks
    dim3 bgrid(NBUCK);                             // 391 buckets

    // ---- bucket-sort build (no global atomics; boff also zeroes sums) ----
    hist_kernel<<<cgrid, blk, 0, stream>>>(ei, hist);
    bscan_kernel<<<bgrid, 512, 0, stream>>>(hist, baseT, colTotal);
    boff_kernel<<<1, 512, 0, stream>>>(colTotal, b_off, sums);
    fillb_kernel<<<cgrid, blk, 0, stream>>>(ei, eattr, baseT, b_off, rec);

    // ---- layer 0: x(d_in) -> xb0; rec.zw: ea -> L0 edge emb ----
    fused_kernel<0, true, true><<<bgrid, fblk, 0, stream>>>(
        rec, b_off, g, gW1, gB1, gW2, gB2,
        eW1, eB1, eW2, eB2,
        x, nW1, nB1, nW2, nB2,
        xb0, sums);

    // ---- layer 1: xb0 -> xb1; rec.zw: L0 -> L1 emb (g1 computed inline) ----
    fused_kernel<1, true, true><<<bgrid, fblk, 0, stream>>>(
        rec, b_off, g, gW1, gB1, gW2, gB2,
        eW1 + 304, eB1 + 16, eW2 + 32, eB2 + 2,
        xb0, nW1 + 176, nB1 + 16, nW2 + 128, nB2 + 8,
        xb1, sums);

    // ---- layer 2: xb1 -> d_out; no rec rewrite, no sums (g2 inline) ----
    fused_kernel<2, false, false><<<bgrid, fblk, 0, stream>>>(
        rec, b_off, g, gW1, gB1, gW2, gB2,
        eW1 + 608, eB1 + 32, eW2 + 64, eB2 + 4,
        xb1, nW1 + 352, nB1 + 32, nW2 + 256, nB2 + 16,
        out, sums);
}